// Round 1
// baseline (1846.196 us; speedup 1.0000x reference)
//
#include <hip/hip_runtime.h>
#include <hip/hip_bf16.h>

#define CDIM 256
#define NPIX 1024
#define NB 16
#define NH 8
#define HD 32

// ---------------------------------------------------------------------------
// Kernel 1: GroupNorm(1 group) stats per sample: mean, rstd over C*H*W
// ---------------------------------------------------------------------------
__global__ __launch_bounds__(256)
void gn_stats_kernel(const float* __restrict__ x, float* __restrict__ stats) {
    int b = blockIdx.x;
    const float4* xb = (const float4*)(x + (size_t)b * CDIM * NPIX);
    int tid = threadIdx.x;
    const int total4 = CDIM * NPIX / 4;  // 65536
    float s = 0.f, ss = 0.f;
    for (int i = tid; i < total4; i += 256) {
        float4 v = xb[i];
        s  += v.x + v.y + v.z + v.w;
        ss += v.x * v.x + v.y * v.y + v.z * v.z + v.w * v.w;
    }
    __shared__ float red0[256];
    __shared__ float red1[256];
    red0[tid] = s; red1[tid] = ss;
    __syncthreads();
    for (int st = 128; st > 0; st >>= 1) {
        if (tid < st) { red0[tid] += red0[tid + st]; red1[tid] += red1[tid + st]; }
        __syncthreads();
    }
    if (tid == 0) {
        const float inv_n = 1.0f / (float)(CDIM * NPIX);
        float mean = red0[0] * inv_n;
        float var  = red1[0] * inv_n - mean * mean;
        stats[b * 2 + 0] = mean;
        stats[b * 2 + 1] = rsqrtf(var + 1e-5f);
    }
}

// ---------------------------------------------------------------------------
// Kernel 2/4: batched 1x1-conv GEMM  Y[b][m][p] = sum_c W[m][c] * X[b][c][p]
//   AFFINE: X is raw x, apply (x - mean)*rstd*gn_w[c] + gn_b[c] on load
//   RESID : add resid[b][m][p] in epilogue
// 64x64 tile, 256 threads, 4x4 microtile, K-chunks of 16.
// ---------------------------------------------------------------------------
template<bool AFFINE, bool RESID>
__global__ __launch_bounds__(256)
void gemm1x1_kernel(const float* __restrict__ Wm,    // [M][CDIM]
                    const float* __restrict__ bias,  // [M]
                    const float* __restrict__ Xin,   // [B][CDIM][NPIX]
                    const float* __restrict__ resid, // [B][M][NPIX] or null
                    const float* __restrict__ gnw,
                    const float* __restrict__ gnb,
                    const float* __restrict__ stats, // [B][2] or null
                    float* __restrict__ Y, int M) {
    const int b  = blockIdx.z;
    const int m0 = blockIdx.y * 64;
    const int p0 = blockIdx.x * 64;
    const float* Xb = Xin + (size_t)b * CDIM * NPIX;

    float mean = 0.f, rstd = 1.f;
    if (AFFINE) { mean = stats[b * 2]; rstd = stats[b * 2 + 1]; }

    __shared__ float As[16][68];  // [k][m], row stride 68 -> float4-aligned, 4-bank skew
    __shared__ float Bs[16][68];  // [k][p]

    const int tid = threadIdx.x;
    const int tx = tid & 15;        // pixel group
    const int ty = tid >> 4;        // row group
    float acc[4][4] = {};

    for (int k0 = 0; k0 < CDIM; k0 += 16) {
        // stage A tile: W[m0+row][k0+kq .. +3], transposed into As[k][m]
        {
            int row = tid >> 2;            // 0..63
            int kq  = (tid & 3) << 2;      // 0,4,8,12
            float4 w4 = *(const float4*)(Wm + (size_t)(m0 + row) * CDIM + k0 + kq);
            As[kq + 0][row] = w4.x;
            As[kq + 1][row] = w4.y;
            As[kq + 2][row] = w4.z;
            As[kq + 3][row] = w4.w;
        }
        // stage B tile: X[k0+kk][p0+pp .. +3]
        {
            int kk = tid >> 4;             // 0..15
            int pp = (tid & 15) << 2;      // 0..60
            int c  = k0 + kk;
            float4 v = *(const float4*)(Xb + (size_t)c * NPIX + p0 + pp);
            if (AFFINE) {
                float sc = rstd * gnw[c];
                float sh = gnb[c] - mean * sc;
                v.x = v.x * sc + sh; v.y = v.y * sc + sh;
                v.z = v.z * sc + sh; v.w = v.w * sc + sh;
            }
            *(float4*)&Bs[kk][pp] = v;
        }
        __syncthreads();
        #pragma unroll
        for (int kk = 0; kk < 16; ++kk) {
            float a[4], bb[4];
            #pragma unroll
            for (int i = 0; i < 4; ++i) a[i] = As[kk][ty * 4 + i];
            #pragma unroll
            for (int j = 0; j < 4; ++j) bb[j] = Bs[kk][tx * 4 + j];
            #pragma unroll
            for (int i = 0; i < 4; ++i)
                #pragma unroll
                for (int j = 0; j < 4; ++j)
                    acc[i][j] = fmaf(a[i], bb[j], acc[i][j]);
        }
        __syncthreads();
    }

    // epilogue
    #pragma unroll
    for (int i = 0; i < 4; ++i) {
        int m = m0 + ty * 4 + i;
        float bs = bias[m];
        size_t off = ((size_t)b * M + m) * NPIX + p0 + tx * 4;
        float4 r;
        r.x = acc[i][0] + bs; r.y = acc[i][1] + bs;
        r.z = acc[i][2] + bs; r.w = acc[i][3] + bs;
        if (RESID) {
            float4 rv = *(const float4*)(resid + off);
            r.x += rv.x; r.y += rv.y; r.z += rv.z; r.w += rv.w;
        }
        *(float4*)(Y + off) = r;
    }
}

// ---------------------------------------------------------------------------
// Kernel 3: flash attention per (b, head, 64-query tile). 1 wave per block.
// qkv layout: [b][3*256][p]; q[d][p] at channel h*32+d, k at 256+h*32+d,
// v at 512+h*32+d. Output aout[b][h*32+d][p] = attention output (pre-proj).
// ---------------------------------------------------------------------------
__global__ __launch_bounds__(64)
void attn_flash_kernel(const float* __restrict__ qkv, float* __restrict__ aout) {
    const int nt   = blockIdx.x;   // query tile
    const int h    = blockIdx.y;
    const int b    = blockIdx.z;
    const int lane = threadIdx.x;  // 0..63

    const size_t base = (size_t)b * (3 * CDIM) * NPIX;
    const float* Q = qkv + base + (size_t)(0 * CDIM + h * HD) * NPIX;
    const float* K = qkv + base + (size_t)(1 * CDIM + h * HD) * NPIX;
    const float* V = qkv + base + (size_t)(2 * CDIM + h * HD) * NPIX;

    const int n = nt * 64 + lane;
    const float scale = 0.17677669529663687f;  // 1/sqrt(32)

    float q[HD];
    #pragma unroll
    for (int d = 0; d < HD; ++d) q[d] = Q[d * NPIX + n] * scale;

    float mrun = -1e30f, l = 0.f;
    float acc[HD] = {};

    __shared__ float Kt[64][HD + 1];
    __shared__ float Vt[64][HD + 1];

    for (int j0 = 0; j0 < NPIX; j0 += 64) {
        __syncthreads();
        #pragma unroll
        for (int d = 0; d < HD; ++d) {
            Kt[lane][d] = K[d * NPIX + j0 + lane];
            Vt[lane][d] = V[d * NPIX + j0 + lane];
        }
        __syncthreads();

        #pragma unroll
        for (int c0 = 0; c0 < 64; c0 += 16) {
            float s[16];
            #pragma unroll
            for (int j = 0; j < 16; ++j) {
                float d0 = 0.f;
                #pragma unroll
                for (int d = 0; d < HD; ++d)
                    d0 = fmaf(q[d], Kt[c0 + j][d], d0);
                s[j] = d0;
            }
            float tmax = s[0];
            #pragma unroll
            for (int j = 1; j < 16; ++j) tmax = fmaxf(tmax, s[j]);
            float mnew = fmaxf(mrun, tmax);
            float corr = __expf(mrun - mnew);
            l *= corr;
            #pragma unroll
            for (int d = 0; d < HD; ++d) acc[d] *= corr;
            #pragma unroll
            for (int j = 0; j < 16; ++j) {
                float p = __expf(s[j] - mnew);
                l += p;
                #pragma unroll
                for (int d = 0; d < HD; ++d)
                    acc[d] = fmaf(p, Vt[c0 + j][d], acc[d]);
            }
            mrun = mnew;
        }
    }

    const float inv_l = 1.0f / l;
    float* O = aout + ((size_t)b * CDIM + h * HD) * NPIX + n;
    #pragma unroll
    for (int d = 0; d < HD; ++d) O[d * NPIX] = acc[d] * inv_l;
}

// ---------------------------------------------------------------------------
extern "C" void kernel_launch(void* const* d_in, const int* in_sizes, int n_in,
                              void* d_out, int out_size, void* d_ws, size_t ws_size,
                              hipStream_t stream) {
    const float* x      = (const float*)d_in[0];
    const float* gn_w   = (const float*)d_in[1];
    const float* gn_b   = (const float*)d_in[2];
    const float* qkv_w  = (const float*)d_in[3];
    const float* qkv_b  = (const float*)d_in[4];
    const float* proj_w = (const float*)d_in[5];
    const float* proj_b = (const float*)d_in[6];
    float* out = (float*)d_out;

    char* ws = (char*)d_ws;
    float* stats = (float*)ws;                                   // 16*2 floats
    float* qkv   = (float*)(ws + 256);                           // 16*768*1024 f32 = 50.3 MB
    float* aout  = (float*)(ws + 256 + (size_t)NB * 3 * CDIM * NPIX * 4);  // 16.8 MB

    gn_stats_kernel<<<NB, 256, 0, stream>>>(x, stats);

    dim3 gQKV(NPIX / 64, (3 * CDIM) / 64, NB);   // (16, 12, 16)
    gemm1x1_kernel<true, false><<<gQKV, 256, 0, stream>>>(
        qkv_w, qkv_b, x, nullptr, gn_w, gn_b, stats, qkv, 3 * CDIM);

    dim3 gATT(NPIX / 64, NH, NB);                // (16, 8, 16)
    attn_flash_kernel<<<gATT, 64, 0, stream>>>(qkv, aout);

    dim3 gPROJ(NPIX / 64, CDIM / 64, NB);        // (16, 4, 16)
    gemm1x1_kernel<false, true><<<gPROJ, 256, 0, stream>>>(
        proj_w, proj_b, aout, x, nullptr, nullptr, nullptr, out, CDIM);
}

// Round 2
// 741.217 us; speedup vs baseline: 2.4908x; 2.4908x over previous
//
#include <hip/hip_runtime.h>
#include <hip/hip_bf16.h>

#define CDIM 256
#define NPIX 1024
#define NB 16
#define NH 8
#define HD 32

// ---------------------------------------------------------------------------
// Kernel 1: GroupNorm(1 group) stats per sample: mean, rstd over C*H*W
// ---------------------------------------------------------------------------
__global__ __launch_bounds__(256)
void gn_stats_kernel(const float* __restrict__ x, float* __restrict__ stats) {
    int b = blockIdx.x;
    const float4* xb = (const float4*)(x + (size_t)b * CDIM * NPIX);
    int tid = threadIdx.x;
    const int total4 = CDIM * NPIX / 4;  // 65536
    float s = 0.f, ss = 0.f;
    for (int i = tid; i < total4; i += 256) {
        float4 v = xb[i];
        s  += v.x + v.y + v.z + v.w;
        ss += v.x * v.x + v.y * v.y + v.z * v.z + v.w * v.w;
    }
    __shared__ float red0[256];
    __shared__ float red1[256];
    red0[tid] = s; red1[tid] = ss;
    __syncthreads();
    for (int st = 128; st > 0; st >>= 1) {
        if (tid < st) { red0[tid] += red0[tid + st]; red1[tid] += red1[tid + st]; }
        __syncthreads();
    }
    if (tid == 0) {
        const float inv_n = 1.0f / (float)(CDIM * NPIX);
        float mean = red0[0] * inv_n;
        float var  = red1[0] * inv_n - mean * mean;
        stats[b * 2 + 0] = mean;
        stats[b * 2 + 1] = rsqrtf(var + 1e-5f);
    }
}

// ---------------------------------------------------------------------------
// Kernel 2/4: batched 1x1-conv GEMM  Y[b][m][p] = sum_c W[m][c] * X[b][c][p]
// 128x128 tile, 256 threads, 8x8 microtile, BK=8.
// 16B-aligned LDS rows (stride 132 floats) -> ds_read_b128 everywhere.
// ---------------------------------------------------------------------------
template<bool AFFINE, bool RESID>
__global__ __launch_bounds__(256)
void gemm1x1_kernel(const float* __restrict__ Wm,    // [M][CDIM]
                    const float* __restrict__ bias,  // [M]
                    const float* __restrict__ Xin,   // [B][CDIM][NPIX]
                    const float* __restrict__ resid, // [B][M][NPIX] or null
                    const float* __restrict__ gnw,
                    const float* __restrict__ gnb,
                    const float* __restrict__ stats, // [B][2] or null
                    float* __restrict__ Y, int M) {
    const int b  = blockIdx.z;
    const int m0 = blockIdx.y * 128;
    const int p0 = blockIdx.x * 128;
    const float* Xb = Xin + (size_t)b * CDIM * NPIX;

    float mean = 0.f, rstd = 1.f;
    if (AFFINE) { mean = stats[b * 2]; rstd = stats[b * 2 + 1]; }

    __shared__ float As[8][132];   // [k][m], 132*4B row stride (16B aligned)
    __shared__ float Bs[8][132];   // [k][p]

    const int tid = threadIdx.x;
    const int tx = tid & 15;        // pixel group (8 cols each)
    const int ty = tid >> 4;        // row group (8 rows each)
    // staging indices
    const int ar = tid >> 1;        // 0..127 : A row
    const int ak = (tid & 1) * 4;   // 0 or 4 : A k-quad
    const int bk = tid >> 5;        // 0..7   : B k
    const int bp = (tid & 31) * 4;  // 0..124 : B pixel quad

    float acc[8][8] = {};

    for (int k0 = 0; k0 < CDIM; k0 += 8) {
        float4 w4 = *(const float4*)(Wm + (size_t)(m0 + ar) * CDIM + k0 + ak);
        int c = k0 + bk;
        float4 xv = *(const float4*)(Xb + (size_t)c * NPIX + p0 + bp);
        if (AFFINE) {
            float sc = rstd * gnw[c];
            float sh = gnb[c] - mean * sc;
            xv.x = xv.x * sc + sh; xv.y = xv.y * sc + sh;
            xv.z = xv.z * sc + sh; xv.w = xv.w * sc + sh;
        }
        __syncthreads();            // previous iter's reads done
        As[ak + 0][ar] = w4.x;
        As[ak + 1][ar] = w4.y;
        As[ak + 2][ar] = w4.z;
        As[ak + 3][ar] = w4.w;
        *(float4*)&Bs[bk][bp] = xv;
        __syncthreads();
        #pragma unroll
        for (int kk = 0; kk < 8; ++kk) {
            float a[8], bb[8];
            *(float4*)&a[0]  = *(const float4*)&As[kk][ty * 8];
            *(float4*)&a[4]  = *(const float4*)&As[kk][ty * 8 + 4];
            *(float4*)&bb[0] = *(const float4*)&Bs[kk][tx * 8];
            *(float4*)&bb[4] = *(const float4*)&Bs[kk][tx * 8 + 4];
            #pragma unroll
            for (int i = 0; i < 8; ++i)
                #pragma unroll
                for (int j = 0; j < 8; ++j)
                    acc[i][j] = fmaf(a[i], bb[j], acc[i][j]);
        }
    }

    // epilogue
    #pragma unroll
    for (int i = 0; i < 8; ++i) {
        int m = m0 + ty * 8 + i;
        float bs = bias[m];
        size_t off = ((size_t)b * M + m) * NPIX + p0 + tx * 8;
        float4 r0, r1;
        r0.x = acc[i][0] + bs; r0.y = acc[i][1] + bs;
        r0.z = acc[i][2] + bs; r0.w = acc[i][3] + bs;
        r1.x = acc[i][4] + bs; r1.y = acc[i][5] + bs;
        r1.z = acc[i][6] + bs; r1.w = acc[i][7] + bs;
        if (RESID) {
            float4 v0 = *(const float4*)(resid + off);
            float4 v1 = *(const float4*)(resid + off + 4);
            r0.x += v0.x; r0.y += v0.y; r0.z += v0.z; r0.w += v0.w;
            r1.x += v1.x; r1.y += v1.y; r1.z += v1.z; r1.w += v1.w;
        }
        *(float4*)(Y + off)     = r0;
        *(float4*)(Y + off + 4) = r1;
    }
}

// ---------------------------------------------------------------------------
// Kernel 3: flash attention. Block = 128 threads (2 waves).
// Each block: 128 query rows of one (b,h); each lane owns 2 rows (n0, n0+64).
// The 2 waves split the KV range (even/odd 64-tiles) with wave-private LDS
// tiles (stride 36 floats -> 16B-aligned b128 broadcast reads), then merge
// partials through LDS at the end.
// ---------------------------------------------------------------------------
__global__ __launch_bounds__(128)
void attn_flash_kernel(const float* __restrict__ qkv, float* __restrict__ aout) {
    const int nt   = blockIdx.x;   // query tile of 128 rows (0..7)
    const int h    = blockIdx.y;
    const int b    = blockIdx.z;
    const int tid  = threadIdx.x;
    const int wave = tid >> 6;
    const int lane = tid & 63;

    __shared__ float smem[2 * 2 * 64 * 36];   // 36864 B
    float* Kw = smem + wave * (2 * 64 * 36);
    float* Vw = Kw + 64 * 36;

    const size_t base = (size_t)b * (3 * CDIM) * NPIX;
    const float* Q = qkv + base + (size_t)(0 * CDIM + h * HD) * NPIX;
    const float* K = qkv + base + (size_t)(1 * CDIM + h * HD) * NPIX;
    const float* V = qkv + base + (size_t)(2 * CDIM + h * HD) * NPIX;

    const int n0 = nt * 128 + lane;
    const float scale = 0.17677669529663687f;  // 1/sqrt(32)

    float q0[HD], q1[HD];
    #pragma unroll
    for (int d = 0; d < HD; ++d) {
        q0[d] = Q[d * NPIX + n0]      * scale;
        q1[d] = Q[d * NPIX + n0 + 64] * scale;
    }

    float mr0 = -1e30f, lr0 = 0.f;
    float mr1 = -1e30f, lr1 = 0.f;
    float acc0[HD] = {}, acc1[HD] = {};

    const int jg = lane & 15;    // kv 4-group
    const int dp = lane >> 4;    // d 8-group

    for (int t = 0; t < 8; ++t) {
        const int j0 = (t * 2 + wave) * 64;
        // ---- stage K/V tile (wave-private, no barrier needed) ----
        #pragma unroll
        for (int dd = 0; dd < 8; ++dd) {
            int d = dp * 8 + dd;
            float4 kv = *(const float4*)(K + (size_t)d * NPIX + j0 + jg * 4);
            float4 vv = *(const float4*)(V + (size_t)d * NPIX + j0 + jg * 4);
            Kw[(jg * 4 + 0) * 36 + d] = kv.x;
            Kw[(jg * 4 + 1) * 36 + d] = kv.y;
            Kw[(jg * 4 + 2) * 36 + d] = kv.z;
            Kw[(jg * 4 + 3) * 36 + d] = kv.w;
            Vw[(jg * 4 + 0) * 36 + d] = vv.x;
            Vw[(jg * 4 + 1) * 36 + d] = vv.y;
            Vw[(jg * 4 + 2) * 36 + d] = vv.z;
            Vw[(jg * 4 + 3) * 36 + d] = vv.w;
        }

        #pragma unroll
        for (int c0 = 0; c0 < 64; c0 += 16) {
            float s0[16], s1[16];
            #pragma unroll
            for (int j = 0; j < 16; ++j) {
                const float* kr = Kw + (c0 + j) * 36;
                float a0 = 0.f, a1 = 0.f;
                #pragma unroll
                for (int dq = 0; dq < 8; ++dq) {
                    float4 k4 = *(const float4*)(kr + dq * 4);
                    a0 = fmaf(q0[dq * 4 + 0], k4.x, a0);
                    a0 = fmaf(q0[dq * 4 + 1], k4.y, a0);
                    a0 = fmaf(q0[dq * 4 + 2], k4.z, a0);
                    a0 = fmaf(q0[dq * 4 + 3], k4.w, a0);
                    a1 = fmaf(q1[dq * 4 + 0], k4.x, a1);
                    a1 = fmaf(q1[dq * 4 + 1], k4.y, a1);
                    a1 = fmaf(q1[dq * 4 + 2], k4.z, a1);
                    a1 = fmaf(q1[dq * 4 + 3], k4.w, a1);
                }
                s0[j] = a0; s1[j] = a1;
            }
            float t0 = s0[0], t1 = s1[0];
            #pragma unroll
            for (int j = 1; j < 16; ++j) { t0 = fmaxf(t0, s0[j]); t1 = fmaxf(t1, s1[j]); }
            float mn0 = fmaxf(mr0, t0);
            float mn1 = fmaxf(mr1, t1);
            float co0 = __expf(mr0 - mn0);
            float co1 = __expf(mr1 - mn1);
            lr0 *= co0; lr1 *= co1;
            #pragma unroll
            for (int d = 0; d < HD; ++d) { acc0[d] *= co0; acc1[d] *= co1; }
            float p0[16], p1[16];
            #pragma unroll
            for (int j = 0; j < 16; ++j) {
                p0[j] = __expf(s0[j] - mn0); lr0 += p0[j];
                p1[j] = __expf(s1[j] - mn1); lr1 += p1[j];
            }
            mr0 = mn0; mr1 = mn1;
            #pragma unroll
            for (int j = 0; j < 16; ++j) {
                const float* vr = Vw + (c0 + j) * 36;
                #pragma unroll
                for (int dq = 0; dq < 8; ++dq) {
                    float4 v4 = *(const float4*)(vr + dq * 4);
                    acc0[dq * 4 + 0] = fmaf(p0[j], v4.x, acc0[dq * 4 + 0]);
                    acc0[dq * 4 + 1] = fmaf(p0[j], v4.y, acc0[dq * 4 + 1]);
                    acc0[dq * 4 + 2] = fmaf(p0[j], v4.z, acc0[dq * 4 + 2]);
                    acc0[dq * 4 + 3] = fmaf(p0[j], v4.w, acc0[dq * 4 + 3]);
                    acc1[dq * 4 + 0] = fmaf(p1[j], v4.x, acc1[dq * 4 + 0]);
                    acc1[dq * 4 + 1] = fmaf(p1[j], v4.y, acc1[dq * 4 + 1]);
                    acc1[dq * 4 + 2] = fmaf(p1[j], v4.z, acc1[dq * 4 + 2]);
                    acc1[dq * 4 + 3] = fmaf(p1[j], v4.w, acc1[dq * 4 + 3]);
                }
            }
        }
    }

    // ---- merge the two waves' partials through LDS ----
    __syncthreads();   // both waves done with K/V tiles
    float* cm = smem;               // [128]
    float* cl = smem + 128;         // [128]
    float* ca = smem + 256;         // [128][33] padded
    if (wave == 1) {
        cm[lane] = mr0; cm[lane + 64] = mr1;
        cl[lane] = lr0; cl[lane + 64] = lr1;
        #pragma unroll
        for (int d = 0; d < HD; ++d) {
            ca[lane * 33 + d]        = acc0[d];
            ca[(lane + 64) * 33 + d] = acc1[d];
        }
    }
    __syncthreads();
    if (wave == 0) {
        float* O = aout + ((size_t)b * CDIM + h * HD) * NPIX + n0;
        {
            float mB = cm[lane], lB = cl[lane];
            float mf = fmaxf(mr0, mB);
            float cA = __expf(mr0 - mf), cB = __expf(mB - mf);
            float inv = 1.0f / (lr0 * cA + lB * cB);
            #pragma unroll
            for (int d = 0; d < HD; ++d)
                O[d * NPIX] = (acc0[d] * cA + ca[lane * 33 + d] * cB) * inv;
        }
        {
            float mB = cm[lane + 64], lB = cl[lane + 64];
            float mf = fmaxf(mr1, mB);
            float cA = __expf(mr1 - mf), cB = __expf(mB - mf);
            float inv = 1.0f / (lr1 * cA + lB * cB);
            #pragma unroll
            for (int d = 0; d < HD; ++d)
                O[d * NPIX + 64] = (acc1[d] * cA + ca[(lane + 64) * 33 + d] * cB) * inv;
        }
    }
}

// ---------------------------------------------------------------------------
extern "C" void kernel_launch(void* const* d_in, const int* in_sizes, int n_in,
                              void* d_out, int out_size, void* d_ws, size_t ws_size,
                              hipStream_t stream) {
    const float* x      = (const float*)d_in[0];
    const float* gn_w   = (const float*)d_in[1];
    const float* gn_b   = (const float*)d_in[2];
    const float* qkv_w  = (const float*)d_in[3];
    const float* qkv_b  = (const float*)d_in[4];
    const float* proj_w = (const float*)d_in[5];
    const float* proj_b = (const float*)d_in[6];
    float* out = (float*)d_out;

    char* ws = (char*)d_ws;
    float* stats = (float*)ws;                                   // 16*2 floats
    float* qkv   = (float*)(ws + 256);                           // 16*768*1024 f32
    float* aout  = (float*)(ws + 256 + (size_t)NB * 3 * CDIM * NPIX * 4);

    gn_stats_kernel<<<NB, 256, 0, stream>>>(x, stats);

    dim3 gQKV(NPIX / 128, (3 * CDIM) / 128, NB);   // (8, 6, 16)
    gemm1x1_kernel<true, false><<<gQKV, 256, 0, stream>>>(
        qkv_w, qkv_b, x, nullptr, gn_w, gn_b, stats, qkv, 3 * CDIM);

    dim3 gATT(NPIX / 128, NH, NB);                 // (8, 8, 16)
    attn_flash_kernel<<<gATT, 128, 0, stream>>>(qkv, aout);

    dim3 gPROJ(NPIX / 128, CDIM / 128, NB);        // (8, 2, 16)
    gemm1x1_kernel<false, true><<<gPROJ, 256, 0, stream>>>(
        proj_w, proj_b, aout, x, nullptr, nullptr, nullptr, out, CDIM);
}

// Round 3
// 319.328 us; speedup vs baseline: 5.7815x; 2.3212x over previous
//
#include <hip/hip_runtime.h>
#include <hip/hip_bf16.h>

typedef short bf16x8 __attribute__((ext_vector_type(8)));
typedef float f32x16 __attribute__((ext_vector_type(16)));
typedef unsigned short ushort8 __attribute__((ext_vector_type(8)));

#define CDIM 256
#define NPIX 1024
#define NB 16
#define NH 8
#define HD 32

static __device__ inline unsigned short f2bf(float f) {
    __hip_bfloat16 h = __float2bfloat16(f);
    return *reinterpret_cast<unsigned short*>(&h);
}

// ---------------------------------------------------------------------------
// Kernel 1: GroupNorm(1 group) stats per sample
// ---------------------------------------------------------------------------
__global__ __launch_bounds__(256)
void gn_stats_kernel(const float* __restrict__ x, float* __restrict__ stats) {
    int b = blockIdx.x;
    const float4* xb = (const float4*)(x + (size_t)b * CDIM * NPIX);
    int tid = threadIdx.x;
    const int total4 = CDIM * NPIX / 4;
    float s = 0.f, ss = 0.f;
    for (int i = tid; i < total4; i += 256) {
        float4 v = xb[i];
        s  += v.x + v.y + v.z + v.w;
        ss += v.x * v.x + v.y * v.y + v.z * v.z + v.w * v.w;
    }
    __shared__ float red0[256];
    __shared__ float red1[256];
    red0[tid] = s; red1[tid] = ss;
    __syncthreads();
    for (int st = 128; st > 0; st >>= 1) {
        if (tid < st) { red0[tid] += red0[tid + st]; red1[tid] += red1[tid + st]; }
        __syncthreads();
    }
    if (tid == 0) {
        const float inv_n = 1.0f / (float)(CDIM * NPIX);
        float mean = red0[0] * inv_n;
        float var  = red1[0] * inv_n - mean * mean;
        stats[b * 2 + 0] = mean;
        stats[b * 2 + 1] = rsqrtf(var + 1e-5f);
    }
}

// ---------------------------------------------------------------------------
// Kernel 2/4: batched 1x1-conv GEMM, fp32 compute.
// MODE 1 (QKV): GroupNorm-affine on input; outputs bf16:
//   Q,K row-major  qkrm[b][sel][h][n][d]   (MFMA A/B fragment feed)
//   V channel-major vcm[b][h][d][n]        (MFMA B fragment feed)
// MODE 0 (proj): f32 out + residual add.
// ---------------------------------------------------------------------------
template<int MODE>
__global__ __launch_bounds__(256)
void gemm1x1_kernel(const float* __restrict__ Wm,    // [M][CDIM]
                    const float* __restrict__ bias,  // [M]
                    const float* __restrict__ Xin,   // [B][CDIM][NPIX]
                    const float* __restrict__ resid, // [B][M][NPIX] or null
                    const float* __restrict__ gnw,
                    const float* __restrict__ gnb,
                    const float* __restrict__ stats, // [B][2] or null
                    float* __restrict__ Yf,
                    unsigned short* __restrict__ qkrm,
                    unsigned short* __restrict__ vcm,
                    int M) {
    const int b  = blockIdx.z;
    const int m0 = blockIdx.y * 128;
    const int p0 = blockIdx.x * 128;
    const float* Xb = Xin + (size_t)b * CDIM * NPIX;

    float mean = 0.f, rstd = 1.f;
    if (MODE == 1) { mean = stats[b * 2]; rstd = stats[b * 2 + 1]; }

    __shared__ float As[8][132];
    __shared__ float Bs[8][132];

    const int tid = threadIdx.x;
    const int tx = tid & 15;
    const int ty = tid >> 4;
    const int ar = tid >> 1;
    const int ak = (tid & 1) * 4;
    const int bk = tid >> 5;
    const int bp = (tid & 31) * 4;

    float acc[8][8] = {};

    for (int k0 = 0; k0 < CDIM; k0 += 8) {
        float4 w4 = *(const float4*)(Wm + (size_t)(m0 + ar) * CDIM + k0 + ak);
        int c = k0 + bk;
        float4 xv = *(const float4*)(Xb + (size_t)c * NPIX + p0 + bp);
        if (MODE == 1) {
            float sc = rstd * gnw[c];
            float sh = gnb[c] - mean * sc;
            xv.x = xv.x * sc + sh; xv.y = xv.y * sc + sh;
            xv.z = xv.z * sc + sh; xv.w = xv.w * sc + sh;
        }
        __syncthreads();
        As[ak + 0][ar] = w4.x;
        As[ak + 1][ar] = w4.y;
        As[ak + 2][ar] = w4.z;
        As[ak + 3][ar] = w4.w;
        *(float4*)&Bs[bk][bp] = xv;
        __syncthreads();
        #pragma unroll
        for (int kk = 0; kk < 8; ++kk) {
            float a[8], bb[8];
            *(float4*)&a[0]  = *(const float4*)&As[kk][ty * 8];
            *(float4*)&a[4]  = *(const float4*)&As[kk][ty * 8 + 4];
            *(float4*)&bb[0] = *(const float4*)&Bs[kk][tx * 8];
            *(float4*)&bb[4] = *(const float4*)&Bs[kk][tx * 8 + 4];
            #pragma unroll
            for (int i = 0; i < 8; ++i)
                #pragma unroll
                for (int j = 0; j < 8; ++j)
                    acc[i][j] = fmaf(a[i], bb[j], acc[i][j]);
        }
    }

    float bs[8];
    #pragma unroll
    for (int i = 0; i < 8; ++i) bs[i] = bias[m0 + ty * 8 + i];

    if (MODE == 0) {
        #pragma unroll
        for (int i = 0; i < 8; ++i) {
            size_t off = ((size_t)b * M + m0 + ty * 8 + i) * NPIX + p0 + tx * 8;
            float4 r0, r1;
            r0.x = acc[i][0] + bs[i]; r0.y = acc[i][1] + bs[i];
            r0.z = acc[i][2] + bs[i]; r0.w = acc[i][3] + bs[i];
            r1.x = acc[i][4] + bs[i]; r1.y = acc[i][5] + bs[i];
            r1.z = acc[i][6] + bs[i]; r1.w = acc[i][7] + bs[i];
            float4 v0 = *(const float4*)(resid + off);
            float4 v1 = *(const float4*)(resid + off + 4);
            r0.x += v0.x; r0.y += v0.y; r0.z += v0.z; r0.w += v0.w;
            r1.x += v1.x; r1.y += v1.y; r1.z += v1.z; r1.w += v1.w;
            *(float4*)(Yf + off)     = r0;
            *(float4*)(Yf + off + 4) = r1;
        }
    } else {
        const int selb = m0 >> 8;                       // 0=Q,1=K,2=V (uniform per block)
        const int hh = ((m0 & 255) + ty * 8) >> 5;      // head
        const int d0 = (ty * 8) & 31;                   // d offset (0,8,16,24)
        if (selb < 2) {
            unsigned short* qk = qkrm + (((size_t)b * 2 + selb) * NH + hh) * NPIX * HD;
            #pragma unroll
            for (int j = 0; j < 8; ++j) {
                int p = p0 + tx * 8 + j;
                ushort8 v;
                #pragma unroll
                for (int i = 0; i < 8; ++i) v[i] = f2bf(acc[i][j] + bs[i]);
                *(ushort8*)(qk + (size_t)p * HD + d0) = v;
            }
        } else {
            unsigned short* vc = vcm + ((size_t)b * NH + hh) * HD * NPIX;
            #pragma unroll
            for (int i = 0; i < 8; ++i) {
                ushort8 v;
                #pragma unroll
                for (int j = 0; j < 8; ++j) v[j] = f2bf(acc[i][j] + bs[i]);
                *(ushort8*)(vc + (size_t)(d0 + i) * NPIX + p0 + tx * 8) = v;
            }
        }
    }
}

// ---------------------------------------------------------------------------
// Kernel 3: MFMA flash attention. Block=256 (4 waves); wave w owns q-tile of
// 32 rows. Swapped QK^T: S^T = mfma(A=K, B=Q) so each lane holds 16 P values
// of ONE q column (q = lane&31); kv rows (r&3)+8*(r>>2)+4*(lane>>5).
// Online softmax with defer-max (THR=8). P packed to bf16 PV A-fragments via
// cvt_pk + shfl_xor(32). O accum D[q][d] (col=d) -> LDS transpose ->
// channel-major f32 aout for the proj GEMM.
// ---------------------------------------------------------------------------
__global__ __launch_bounds__(256)
void attn_mfma_kernel(const unsigned short* __restrict__ qkrm,
                      const unsigned short* __restrict__ vcm,
                      float* __restrict__ aout) {
    const int wave = threadIdx.x >> 6;
    const int lane = threadIdx.x & 63;
    const int ql   = lane & 31;
    const int hi   = lane >> 5;
    const int h = blockIdx.y, b = blockIdx.z;
    const int q0 = blockIdx.x * 128 + wave * 32;

    const unsigned short* Qb = qkrm + (((size_t)b * 2 + 0) * NH + h) * NPIX * HD;
    const unsigned short* Kb = qkrm + (((size_t)b * 2 + 1) * NH + h) * NPIX * HD;
    const unsigned short* Vb = vcm  + (((size_t)b * NH + h) * HD) * NPIX;

    // Q fragments (B-operand): col=q=lane&31, k = d = s*16 + hi*8 + r
    bf16x8 qf0 = *(const bf16x8*)(Qb + (size_t)(q0 + ql) * HD + hi * 8);
    bf16x8 qf1 = *(const bf16x8*)(Qb + (size_t)(q0 + ql) * HD + 16 + hi * 8);

    f32x16 acc = {};
    float mrun = -1e30f, lsum = 0.f;
    const float scale = 0.17677669529663687f;  // 1/sqrt(32)

    for (int kv0 = 0; kv0 < NPIX; kv0 += 32) {
        // K fragments (A-operand): row=kv=lane&31, k = d slice
        bf16x8 kf0 = *(const bf16x8*)(Kb + (size_t)(kv0 + ql) * HD + hi * 8);
        bf16x8 kf1 = *(const bf16x8*)(Kb + (size_t)(kv0 + ql) * HD + 16 + hi * 8);
        // V fragments (B-operand of PV): col=d=lane&31, k = kv slice of 8
        bf16x8 vf0 = *(const bf16x8*)(Vb + (size_t)ql * NPIX + kv0 + hi * 8);
        bf16x8 vf1 = *(const bf16x8*)(Vb + (size_t)ql * NPIX + kv0 + 16 + hi * 8);

        f32x16 st = {};
        st = __builtin_amdgcn_mfma_f32_32x32x16_bf16(kf0, qf0, st, 0, 0, 0);
        st = __builtin_amdgcn_mfma_f32_32x32x16_bf16(kf1, qf1, st, 0, 0, 0);

        float p[16];
        float vmax = -1e30f;
        #pragma unroll
        for (int r = 0; r < 16; ++r) { p[r] = st[r] * scale; vmax = fmaxf(vmax, p[r]); }
        float pmax = fmaxf(vmax, __shfl_xor(vmax, 32));
        if (!__all(pmax - mrun <= 8.f)) {
            float mnew = fmaxf(mrun, pmax);
            float corr = __expf(mrun - mnew);
            lsum *= corr;
            #pragma unroll
            for (int j = 0; j < 16; ++j) {
                float cj = __shfl(corr, (j & 3) + 8 * (j >> 2) + 4 * hi);
                acc[j] *= cj;
            }
            mrun = mnew;
        }
        float ts = 0.f;
        #pragma unroll
        for (int r = 0; r < 16; ++r) { p[r] = __expf(p[r] - mrun); ts += p[r]; }
        lsum += ts;

        // pack P to bf16 pairs: pk[i] = (p[2i] lo, p[2i+1] hi)
        unsigned pk[8];
        #pragma unroll
        for (int i = 0; i < 8; ++i) {
            unsigned r_;
            asm("v_cvt_pk_bf16_f32 %0, %1, %2" : "=v"(r_) : "v"(p[2 * i]), "v"(p[2 * i + 1]));
            pk[i] = r_;
        }
        unsigned x0 = __shfl_xor((int)pk[0], 32), x1 = __shfl_xor((int)pk[1], 32);
        unsigned x2 = __shfl_xor((int)pk[2], 32), x3 = __shfl_xor((int)pk[3], 32);
        unsigned x4 = __shfl_xor((int)pk[4], 32), x5 = __shfl_xor((int)pk[5], 32);
        unsigned x6 = __shfl_xor((int)pk[6], 32), x7 = __shfl_xor((int)pk[7], 32);
        // PV A-fragment words: lane(q,hi) needs P[q][16j + 8hi + 2w, +2w+1]
        union { unsigned u[4]; bf16x8 v; } pa0, pa1;
        pa0.u[0] = hi ? x2    : pk[0];
        pa0.u[1] = hi ? x3    : pk[1];
        pa0.u[2] = hi ? pk[2] : x0;
        pa0.u[3] = hi ? pk[3] : x1;
        pa1.u[0] = hi ? x6    : pk[4];
        pa1.u[1] = hi ? x7    : pk[5];
        pa1.u[2] = hi ? pk[6] : x4;
        pa1.u[3] = hi ? pk[7] : x5;

        acc = __builtin_amdgcn_mfma_f32_32x32x16_bf16(pa0.v, vf0, acc, 0, 0, 0);
        acc = __builtin_amdgcn_mfma_f32_32x32x16_bf16(pa1.v, vf1, acc, 0, 0, 0);
    }

    float ltot = lsum + __shfl_xor(lsum, 32);
    float inv = 1.0f / ltot;

    // O epilogue: acc rows q=(j&3)+8*(j>>2)+4*hi, col d=lane&31.
    // Normalize (inv lives in lane-space q) then LDS-transpose to
    // channel-major coalesced stores.
    __shared__ float olds[4][32 * 33];
    float* ow = olds[wave];
    #pragma unroll
    for (int j = 0; j < 16; ++j) {
        int qr = (j & 3) + 8 * (j >> 2) + 4 * hi;
        float ij = __shfl(inv, qr);
        ow[qr * 33 + ql] = acc[j] * ij;
    }
    asm volatile("s_waitcnt lgkmcnt(0)" ::: "memory");
    #pragma unroll
    for (int it = 0; it < 16; ++it) {
        int dr = it * 2 + hi;
        float v = ow[ql * 33 + dr];
        aout[((size_t)b * CDIM + h * HD + dr) * NPIX + q0 + ql] = v;
    }
}

// ---------------------------------------------------------------------------
extern "C" void kernel_launch(void* const* d_in, const int* in_sizes, int n_in,
                              void* d_out, int out_size, void* d_ws, size_t ws_size,
                              hipStream_t stream) {
    const float* x      = (const float*)d_in[0];
    const float* gn_w   = (const float*)d_in[1];
    const float* gn_b   = (const float*)d_in[2];
    const float* qkv_w  = (const float*)d_in[3];
    const float* qkv_b  = (const float*)d_in[4];
    const float* proj_w = (const float*)d_in[5];
    const float* proj_b = (const float*)d_in[6];
    float* out = (float*)d_out;

    char* ws = (char*)d_ws;
    float* stats = (float*)ws;                                        // 128 B used
    unsigned short* qkrm = (unsigned short*)(ws + 256);               // 16.78 MB
    unsigned short* vcm  = qkrm + (size_t)NB * 2 * NH * NPIX * HD;    // 8.39 MB
    float* aout = (float*)(vcm + (size_t)NB * NH * HD * NPIX);        // 16.78 MB

    gn_stats_kernel<<<NB, 256, 0, stream>>>(x, stats);

    dim3 gQKV(NPIX / 128, (3 * CDIM) / 128, NB);   // (8, 6, 16)
    gemm1x1_kernel<1><<<gQKV, 256, 0, stream>>>(
        qkv_w, qkv_b, x, nullptr, gn_w, gn_b, stats, nullptr, qkrm, vcm, 3 * CDIM);

    dim3 gATT(NPIX / 128, NH, NB);                 // (8, 8, 16)
    attn_mfma_kernel<<<gATT, 256, 0, stream>>>(qkrm, vcm, aout);

    dim3 gPROJ(NPIX / 128, CDIM / 128, NB);        // (8, 2, 16)
    gemm1x1_kernel<0><<<gPROJ, 256, 0, stream>>>(
        proj_w, proj_b, aout, x, nullptr, nullptr, nullptr, out, nullptr, nullptr, CDIM);
}

// Round 4
// 196.099 us; speedup vs baseline: 9.4146x; 1.6284x over previous
//
#include <hip/hip_runtime.h>
#include <hip/hip_bf16.h>

typedef short bf16x8 __attribute__((ext_vector_type(8)));
typedef float f32x16 __attribute__((ext_vector_type(16)));
typedef unsigned short ushort8 __attribute__((ext_vector_type(8)));
typedef unsigned short ushort4v __attribute__((ext_vector_type(4)));

#define CDIM 256
#define NPIX 1024
#define NB 16
#define NH 8
#define HD 32
// scale * log2(e): softmax done in exp2 domain
#define QSCALE (0.17677669529663687f * 1.4426950408889634f)

static __device__ inline unsigned short f2bf(float f) {
    __hip_bfloat16 h = __float2bfloat16(f);
    return *reinterpret_cast<unsigned short*>(&h);
}

// ---------------------------------------------------------------------------
// Kernel 1a: partial sums for GroupNorm stats. grid (slice=16, b=16).
// ---------------------------------------------------------------------------
__global__ __launch_bounds__(256)
void gn_partial_kernel(const float* __restrict__ x, float* __restrict__ partial) {
    const int slice = blockIdx.x, b = blockIdx.y;
    const float4* xb = (const float4*)(x + (size_t)b * CDIM * NPIX + slice * 16384);
    const int tid = threadIdx.x;
    float s = 0.f, ss = 0.f;
    #pragma unroll
    for (int i = 0; i < 16; ++i) {
        float4 v = xb[tid + i * 256];
        s  += v.x + v.y + v.z + v.w;
        ss += v.x * v.x + v.y * v.y + v.z * v.z + v.w * v.w;
    }
    __shared__ float r0[256], r1[256];
    r0[tid] = s; r1[tid] = ss;
    __syncthreads();
    for (int st = 128; st > 0; st >>= 1) {
        if (tid < st) { r0[tid] += r0[tid + st]; r1[tid] += r1[tid + st]; }
        __syncthreads();
    }
    if (tid == 0) {
        partial[(b * 16 + slice) * 2 + 0] = r0[0];
        partial[(b * 16 + slice) * 2 + 1] = r1[0];
    }
}

// Kernel 1b: finalize stats. grid 16 blocks x 64 thr.
__global__ __launch_bounds__(64)
void gn_final_kernel(const float* __restrict__ partial, float* __restrict__ stats) {
    const int b = blockIdx.x, t = threadIdx.x;
    float s = 0.f, ss = 0.f;
    if (t < 16) { s = partial[(b * 16 + t) * 2]; ss = partial[(b * 16 + t) * 2 + 1]; }
    #pragma unroll
    for (int m = 8; m >= 1; m >>= 1) { s += __shfl_xor(s, m); ss += __shfl_xor(ss, m); }
    if (t == 0) {
        const float inv_n = 1.0f / (float)(CDIM * NPIX);
        float mean = s * inv_n;
        float var  = ss * inv_n - mean * mean;
        stats[b * 2 + 0] = mean;
        stats[b * 2 + 1] = rsqrtf(var + 1e-5f);
    }
}

// ---------------------------------------------------------------------------
// Kernel 2: weights f32 -> bf16 (qkv_w then proj_w, concatenated).
// ---------------------------------------------------------------------------
__global__ __launch_bounds__(256)
void wconv_kernel(const float* __restrict__ qw, const float* __restrict__ pw,
                  unsigned short* __restrict__ wqb, unsigned short* __restrict__ wpb) {
    int idx = blockIdx.x * 256 + threadIdx.x;
    #pragma unroll
    for (int i = 0; i < 4; ++i) {
        int j = idx + i * 65536;
        if (j < 768 * 256) wqb[j] = f2bf(qw[j]);
        else               wpb[j - 768 * 256] = f2bf(pw[j - 768 * 256]);
    }
}

// ---------------------------------------------------------------------------
// Kernel 3: xnbT[b][p][c] bf16 = GroupNorm-affine(x[b][c][p]).  64x64 tiles.
// grid (ptile=16, ctile=4, b=16), 256 thr.
// ---------------------------------------------------------------------------
__global__ __launch_bounds__(256)
void xnbt_kernel(const float* __restrict__ x, const float* __restrict__ gnw,
                 const float* __restrict__ gnb, const float* __restrict__ stats,
                 unsigned short* __restrict__ xnbT) {
    const int p0 = blockIdx.x * 64, c0 = blockIdx.y * 64, b = blockIdx.z;
    const int q = threadIdx.x >> 6, l = threadIdx.x & 63;
    const float mean = stats[b * 2], rstd = stats[b * 2 + 1];
    __shared__ float L[64][65];
    const float* xb = x + (size_t)b * CDIM * NPIX;
    #pragma unroll
    for (int i = 0; i < 16; ++i) {
        int ci = q * 16 + i;
        int c = c0 + ci;
        float sc = rstd * gnw[c];
        float sh = gnb[c] - mean * sc;
        L[ci][l] = xb[(size_t)c * NPIX + p0 + l] * sc + sh;
    }
    __syncthreads();
    unsigned short* ob = xnbT + ((size_t)b * NPIX + p0) * CDIM + c0;
    #pragma unroll
    for (int i = 0; i < 16; ++i) {
        int pi = q * 16 + i;
        ob[(size_t)pi * CDIM + l] = f2bf(L[l][pi]);
    }
}

// ---------------------------------------------------------------------------
// Kernel 4: QKV GEMM, bf16 MFMA. Y[m][p] = sum_c W[m][c]*Xn[p][c].
// Block 256 (4 waves 2x2), tile 128x128, fragments direct from L2.
// Epilogue -> qkrm (Q scaled by QSCALE) / vcm bf16 layouts.
// ---------------------------------------------------------------------------
__global__ __launch_bounds__(256)
void qkv_gemm_kernel(const unsigned short* __restrict__ wqb,
                     const float* __restrict__ bias,
                     const unsigned short* __restrict__ xnbT,
                     unsigned short* __restrict__ qkrm,
                     unsigned short* __restrict__ vcm) {
    const int b = blockIdx.z;
    const int m0 = blockIdx.y * 128, p0 = blockIdx.x * 128;
    const int wave = threadIdx.x >> 6, lane = threadIdx.x & 63;
    const int ql = lane & 31, hi = lane >> 5;
    const int wr = wave >> 1, wc = wave & 1;

    const unsigned short* Abase = wqb + (size_t)(m0 + wr * 64) * CDIM;
    const unsigned short* Bbase = xnbT + ((size_t)b * NPIX + p0 + wc * 64) * CDIM;

    f32x16 acc[2][2] = {};
    #pragma unroll
    for (int k0 = 0; k0 < CDIM; k0 += 16) {
        bf16x8 a0 = *(const bf16x8*)(Abase + (size_t)(ql) * CDIM + k0 + hi * 8);
        bf16x8 a1 = *(const bf16x8*)(Abase + (size_t)(32 + ql) * CDIM + k0 + hi * 8);
        bf16x8 b0 = *(const bf16x8*)(Bbase + (size_t)(ql) * CDIM + k0 + hi * 8);
        bf16x8 b1 = *(const bf16x8*)(Bbase + (size_t)(32 + ql) * CDIM + k0 + hi * 8);
        acc[0][0] = __builtin_amdgcn_mfma_f32_32x32x16_bf16(a0, b0, acc[0][0], 0, 0, 0);
        acc[0][1] = __builtin_amdgcn_mfma_f32_32x32x16_bf16(a0, b1, acc[0][1], 0, 0, 0);
        acc[1][0] = __builtin_amdgcn_mfma_f32_32x32x16_bf16(a1, b0, acc[1][0], 0, 0, 0);
        acc[1][1] = __builtin_amdgcn_mfma_f32_32x32x16_bf16(a1, b1, acc[1][1], 0, 0, 0);
    }

    #pragma unroll
    for (int mt = 0; mt < 2; ++mt) {
        const int m_sub = m0 + wr * 64 + mt * 32;
        const int sel = m_sub >> 8;
        const int hh = (m_sub >> 5) & 7;
        #pragma unroll
        for (int pt = 0; pt < 2; ++pt) {
            const int p = p0 + wc * 64 + pt * 32 + ql;
            if (sel < 2) {
                const float qs = (sel == 0) ? QSCALE : 1.0f;
                unsigned short* qk = qkrm + (((size_t)b * 2 + sel) * NH + hh) * NPIX * HD;
                #pragma unroll
                for (int rg = 0; rg < 4; ++rg) {
                    const int dbase = rg * 8 + hi * 4;
                    ushort4v w;
                    #pragma unroll
                    for (int j = 0; j < 4; ++j)
                        w[j] = f2bf((acc[mt][pt][rg * 4 + j] + bias[m_sub + dbase + j]) * qs);
                    *(ushort4v*)(qk + (size_t)p * HD + dbase) = w;
                }
            } else {
                unsigned short* vc = vcm + ((size_t)b * NH + hh) * HD * NPIX;
                #pragma unroll
                for (int r = 0; r < 16; ++r) {
                    const int d = (r & 3) + 8 * (r >> 2) + 4 * hi;
                    vc[(size_t)d * NPIX + p] = f2bf(acc[mt][pt][r] + bias[m_sub + d]);
                }
            }
        }
    }
}

// ---------------------------------------------------------------------------
// Kernel 5: MFMA flash attention, LDS-staged K/V (KVBLK=64, double-buffered),
// exp2-domain softmax (scale*log2e folded into Q), defer-max.
// Grid: 1024 blocks 1-D, XCD-grouping decode. Block 256 = 4 waves (q-subtiles).
// Output bf16 aoutT[b][p][c].
// ---------------------------------------------------------------------------
__global__ __launch_bounds__(256)
void attn_mfma_kernel(const unsigned short* __restrict__ qkrm,
                      const unsigned short* __restrict__ vcm,
                      unsigned short* __restrict__ aoutT) {
    const int d = blockIdx.x;
    const int xcd = d & 7, i = d >> 3;
    const int qt = i & 7;
    const int pr = (xcd << 4) | (i >> 3);
    const int h = pr & 7, b = pr >> 3;

    const int tid = threadIdx.x;
    const int wave = tid >> 6, lane = tid & 63;
    const int ql = lane & 31, hi = lane >> 5;
    const int q0 = qt * 128 + wave * 32;

    const unsigned short* Qb = qkrm + (((size_t)b * 2 + 0) * NH + h) * NPIX * HD;
    const unsigned short* Kb = qkrm + (((size_t)b * 2 + 1) * NH + h) * NPIX * HD;
    const unsigned short* Vb = vcm  + ((size_t)b * NH + h) * HD * NPIX;

    __shared__ unsigned short Kl[2][64 * 40];   // pad: row stride 40 (80B)
    __shared__ unsigned short Vl[2][32 * 72];   // pad: row stride 72 (144B)

    bf16x8 qf0 = *(const bf16x8*)(Qb + (size_t)(q0 + ql) * HD + hi * 8);
    bf16x8 qf1 = *(const bf16x8*)(Qb + (size_t)(q0 + ql) * HD + 16 + hi * 8);

    f32x16 acc = {};
    float mrun = -1e30f, lsum = 0.f;

    const int krow = tid >> 2, kcol = (tid & 3) * 8;      // K stage map
    const int vrow = tid >> 3, vcol = (tid & 7) * 8;      // V stage map

    ushort8 kreg = *(const ushort8*)(Kb + (size_t)krow * HD + kcol);
    ushort8 vreg = *(const ushort8*)(Vb + (size_t)vrow * NPIX + vcol);
    *(ushort8*)&Kl[0][krow * 40 + kcol] = kreg;
    *(ushort8*)&Vl[0][vrow * 72 + vcol] = vreg;
    kreg = *(const ushort8*)(Kb + (size_t)(64 + krow) * HD + kcol);
    vreg = *(const ushort8*)(Vb + (size_t)vrow * NPIX + 64 + vcol);

    int cur = 0;
    for (int step = 0; step < 16; ++step) {
        __syncthreads();
        if (step + 1 < 16) {
            *(ushort8*)&Kl[cur ^ 1][krow * 40 + kcol] = kreg;
            *(ushort8*)&Vl[cur ^ 1][vrow * 72 + vcol] = vreg;
        }
        if (step + 2 < 16) {
            const int kv = (step + 2) * 64;
            kreg = *(const ushort8*)(Kb + (size_t)(kv + krow) * HD + kcol);
            vreg = *(const ushort8*)(Vb + (size_t)vrow * NPIX + kv + vcol);
        }

        #pragma unroll
        for (int u = 0; u < 2; ++u) {
            const unsigned short* Kr = &Kl[cur][(u * 32 + ql) * 40];
            bf16x8 kf0 = *(const bf16x8*)(Kr + hi * 8);
            bf16x8 kf1 = *(const bf16x8*)(Kr + 16 + hi * 8);
            f32x16 st = {};
            st = __builtin_amdgcn_mfma_f32_32x32x16_bf16(kf0, qf0, st, 0, 0, 0);
            st = __builtin_amdgcn_mfma_f32_32x32x16_bf16(kf1, qf1, st, 0, 0, 0);

            float vmax = st[0];
            #pragma unroll
            for (int r = 1; r < 16; ++r) vmax = fmaxf(vmax, st[r]);
            float pmax = fmaxf(vmax, __shfl_xor(vmax, 32));
            if (!__all(pmax - mrun <= 11.5f)) {
                float mnew = fmaxf(mrun, pmax);
                float corr = exp2f(mrun - mnew);
                lsum *= corr;
                #pragma unroll
                for (int j = 0; j < 16; ++j) {
                    float cj = __shfl(corr, (j & 3) + 8 * (j >> 2) + 4 * hi);
                    acc[j] *= cj;
                }
                mrun = mnew;
            }
            float p[16];
            float ts = 0.f;
            #pragma unroll
            for (int r = 0; r < 16; ++r) { p[r] = exp2f(st[r] - mrun); ts += p[r]; }
            lsum += ts;

            unsigned pk[8];
            #pragma unroll
            for (int k2 = 0; k2 < 8; ++k2) {
                unsigned r_;
                asm("v_cvt_pk_bf16_f32 %0, %1, %2" : "=v"(r_) : "v"(p[2 * k2]), "v"(p[2 * k2 + 1]));
                pk[k2] = r_;
            }
            unsigned x0 = __shfl_xor((int)pk[0], 32), x1 = __shfl_xor((int)pk[1], 32);
            unsigned x2 = __shfl_xor((int)pk[2], 32), x3 = __shfl_xor((int)pk[3], 32);
            unsigned x4 = __shfl_xor((int)pk[4], 32), x5 = __shfl_xor((int)pk[5], 32);
            unsigned x6 = __shfl_xor((int)pk[6], 32), x7 = __shfl_xor((int)pk[7], 32);
            union { unsigned u_[4]; bf16x8 v; } pa0, pa1;
            pa0.u_[0] = hi ? x2    : pk[0];
            pa0.u_[1] = hi ? x3    : pk[1];
            pa0.u_[2] = hi ? pk[2] : x0;
            pa0.u_[3] = hi ? pk[3] : x1;
            pa1.u_[0] = hi ? x6    : pk[4];
            pa1.u_[1] = hi ? x7    : pk[5];
            pa1.u_[2] = hi ? pk[6] : x4;
            pa1.u_[3] = hi ? pk[7] : x5;

            const unsigned short* Vr = &Vl[cur][ql * 72 + u * 32];
            bf16x8 vf0 = *(const bf16x8*)(Vr + hi * 8);
            bf16x8 vf1 = *(const bf16x8*)(Vr + 16 + hi * 8);
            acc = __builtin_amdgcn_mfma_f32_32x32x16_bf16(pa0.v, vf0, acc, 0, 0, 0);
            acc = __builtin_amdgcn_mfma_f32_32x32x16_bf16(pa1.v, vf1, acc, 0, 0, 0);
        }
        cur ^= 1;
    }

    float ltot = lsum + __shfl_xor(lsum, 32);
    float inv = 1.0f / ltot;
    unsigned short* ob = aoutT + ((size_t)b * NPIX + q0) * CDIM + h * HD;
    #pragma unroll
    for (int j = 0; j < 16; ++j) {
        int qr = (j & 3) + 8 * (j >> 2) + 4 * hi;
        float ij = __shfl(inv, qr);
        ob[(size_t)qr * CDIM + ql] = f2bf(acc[j] * ij);
    }
}

// ---------------------------------------------------------------------------
// Kernel 6: proj GEMM, bf16 MFMA + bias + fp32 residual. Same shape as QKV.
// ---------------------------------------------------------------------------
__global__ __launch_bounds__(256)
void proj_gemm_kernel(const unsigned short* __restrict__ wpb,
                      const float* __restrict__ bias,
                      const unsigned short* __restrict__ aoutT,
                      const float* __restrict__ xres,
                      float* __restrict__ out) {
    const int b = blockIdx.z;
    const int m0 = blockIdx.y * 128, p0 = blockIdx.x * 128;
    const int wave = threadIdx.x >> 6, lane = threadIdx.x & 63;
    const int ql = lane & 31, hi = lane >> 5;
    const int wr = wave >> 1, wc = wave & 1;

    const unsigned short* Abase = wpb + (size_t)(m0 + wr * 64) * CDIM;
    const unsigned short* Bbase = aoutT + ((size_t)b * NPIX + p0 + wc * 64) * CDIM;

    f32x16 acc[2][2] = {};
    #pragma unroll
    for (int k0 = 0; k0 < CDIM; k0 += 16) {
        bf16x8 a0 = *(const bf16x8*)(Abase + (size_t)(ql) * CDIM + k0 + hi * 8);
        bf16x8 a1 = *(const bf16x8*)(Abase + (size_t)(32 + ql) * CDIM + k0 + hi * 8);
        bf16x8 b0 = *(const bf16x8*)(Bbase + (size_t)(ql) * CDIM + k0 + hi * 8);
        bf16x8 b1 = *(const bf16x8*)(Bbase + (size_t)(32 + ql) * CDIM + k0 + hi * 8);
        acc[0][0] = __builtin_amdgcn_mfma_f32_32x32x16_bf16(a0, b0, acc[0][0], 0, 0, 0);
        acc[0][1] = __builtin_amdgcn_mfma_f32_32x32x16_bf16(a0, b1, acc[0][1], 0, 0, 0);
        acc[1][0] = __builtin_amdgcn_mfma_f32_32x32x16_bf16(a1, b0, acc[1][0], 0, 0, 0);
        acc[1][1] = __builtin_amdgcn_mfma_f32_32x32x16_bf16(a1, b1, acc[1][1], 0, 0, 0);
    }

    #pragma unroll
    for (int mt = 0; mt < 2; ++mt) {
        const int m_sub = m0 + wr * 64 + mt * 32;
        #pragma unroll
        for (int pt = 0; pt < 2; ++pt) {
            const int p = p0 + wc * 64 + pt * 32 + ql;
            #pragma unroll
            for (int r = 0; r < 16; ++r) {
                const int m = m_sub + (r & 3) + 8 * (r >> 2) + 4 * hi;
                const size_t off = ((size_t)b * CDIM + m) * NPIX + p;
                out[off] = acc[mt][pt][r] + bias[m] + xres[off];
            }
        }
    }
}

// ---------------------------------------------------------------------------
extern "C" void kernel_launch(void* const* d_in, const int* in_sizes, int n_in,
                              void* d_out, int out_size, void* d_ws, size_t ws_size,
                              hipStream_t stream) {
    const float* x      = (const float*)d_in[0];
    const float* gn_w   = (const float*)d_in[1];
    const float* gn_b   = (const float*)d_in[2];
    const float* qkv_w  = (const float*)d_in[3];
    const float* qkv_b  = (const float*)d_in[4];
    const float* proj_w = (const float*)d_in[5];
    const float* proj_b = (const float*)d_in[6];
    float* out = (float*)d_out;

    char* ws = (char*)d_ws;
    size_t off = 0;
    float* partial = (float*)(ws + off); off += 2048;
    float* stats   = (float*)(ws + off); off += 512;
    unsigned short* wqb  = (unsigned short*)(ws + off); off += (size_t)768 * 256 * 2;
    unsigned short* wpb  = (unsigned short*)(ws + off); off += (size_t)256 * 256 * 2;
    unsigned short* xnbT = (unsigned short*)(ws + off); off += (size_t)NB * NPIX * CDIM * 2;
    unsigned short* qkrm = (unsigned short*)(ws + off); off += (size_t)NB * 2 * NH * NPIX * HD * 2;
    unsigned short* vcm  = (unsigned short*)(ws + off); off += (size_t)NB * NH * HD * NPIX * 2;
    unsigned short* aoutT = (unsigned short*)(ws + off);

    gn_partial_kernel<<<dim3(16, 16), 256, 0, stream>>>(x, partial);
    gn_final_kernel<<<16, 64, 0, stream>>>(partial, stats);
    wconv_kernel<<<256, 256, 0, stream>>>(qkv_w, proj_w, wqb, wpb);
    xnbt_kernel<<<dim3(16, 4, 16), 256, 0, stream>>>(x, gn_w, gn_b, stats, xnbT);

    qkv_gemm_kernel<<<dim3(NPIX / 128, 6, NB), 256, 0, stream>>>(
        wqb, qkv_b, xnbT, qkrm, vcm);

    attn_mfma_kernel<<<1024, 256, 0, stream>>>(qkrm, vcm, aoutT);

    proj_gemm_kernel<<<dim3(NPIX / 128, 2, NB), 256, 0, stream>>>(
        wpb, proj_b, aoutT, x, out);
}